// Round 1
// baseline (4972.424 us; speedup 1.0000x reference)
//
#include <hip/hip_runtime.h>
#include <hip/hip_fp16.h>

// SoftRR: n=1024, m=8192, rounds=8, TAU=1.0
//   scan over 8192 rows (V tiled x8):
//     y = softmax((row - min(row) + 1) * c);  c = (1-y)*c
//   pi[i][j] = sum over rounds of y
//
// R5: latency-restructured scan. R4 measured 1424 cy/step with ~72% VALU-busy
// on the active CU: everything after the barrier depended on Sinv_s, so the
// ~160cy sP-read window and barrier skew were dead time, and y/pack/store
// serialized behind the reduce. Now:
//   - y_{s-1} = e_{s-1}*Sinv_{s-1}, pack, and the R-store execute in step s's
//     sP-read shadow (one-step deferral; Sinv/e of the previous step are kept).
//   - t = c*e precomputed in the window; on-chain c-update is a single fma.
//   - chain = ds_read -> dpp3 -> readlane -> rcp -> fma -> fma_mix -> exp2
//     -> tree -> dpp6 -> ds_write -> barrier.
//   - x4 unroll with ping-pong e arrays + 4 A-buffers: zero rotation movs,
//     all array indexing compile-time constant (no scratch).

#define N_ROWS 1024
#define M_COLS 8192
#define STEPS  8192
#define LOG2E  1.4426950408889634f

using half8  = __attribute__((ext_vector_type(8))) _Float16;
using half2v = __attribute__((ext_vector_type(2))) _Float16;

__device__ __forceinline__ float fast_exp2(float x) {
#if __has_builtin(__builtin_amdgcn_exp2f)
  return __builtin_amdgcn_exp2f(x);
#else
  return exp2f(x);
#endif
}
__device__ __forceinline__ float fast_rcp(float x) {
#if __has_builtin(__builtin_amdgcn_rcpf)
  return __builtin_amdgcn_rcpf(x);
#else
  return 1.0f / x;
#endif
}
__device__ __forceinline__ half2v pack_f16(float y0, float y1) {
  return __builtin_bit_cast(half2v, __builtin_amdgcn_cvt_pkrtz(y0, y1));
}

template <int CTRL>
__device__ __forceinline__ float dpp_add(float x) {
  int yi = __builtin_amdgcn_update_dpp(0, __builtin_bit_cast(int, x),
                                       CTRL, 0xf, 0xf, true);
  return x + __builtin_bit_cast(float, yi);
}

// full 64-lane sum; result valid in lane 63
__device__ __forceinline__ float wave_sum_to_lane63(float x) {
  x = dpp_add<0x111>(x);  // row_shr:1
  x = dpp_add<0x112>(x);  // row_shr:2
  x = dpp_add<0x114>(x);  // row_shr:4
  x = dpp_add<0x118>(x);  // row_shr:8   -> lane15 of each row = row sum
  x = dpp_add<0x142>(x);  // row_bcast15
  x = dpp_add<0x143>(x);  // row_bcast31 -> lane63 = total
  return x;
}

// barrier WITHOUT vmcnt drain: only LDS ops must be visible across it
#define BAR_LDS_ONLY() asm volatile("s_waitcnt lgkmcnt(0)\n\ts_barrier" ::: "memory")

// ---------------- rowmin: one block per row ----------------
__global__ void softrr_rowmin(const float* __restrict__ V, float* __restrict__ rmin) {
  const int row = blockIdx.x;
  const float* p = V + (size_t)row * M_COLS;
  float m = 1e30f;
  for (int j = threadIdx.x; j < M_COLS; j += 256) m = fminf(m, p[j]);
#pragma unroll
  for (int off = 32; off; off >>= 1) m = fminf(m, __shfl_xor(m, off, 64));
  __shared__ float sm[4];
  if ((threadIdx.x & 63) == 0) sm[threadIdx.x >> 6] = m;
  __syncthreads();
  if (threadIdx.x == 0) {
    rmin[row] = fminf(fminf(sm[0], sm[1]), fminf(sm[2], sm[3]));
  }
}

// ---------------- prep: a = (V - rowmin + 1) * log2e, fp16 ----------------
__global__ void softrr_prep(const float* __restrict__ V, const float* __restrict__ rmin,
                            __half* __restrict__ A) {
  const int idx8 = blockIdx.x * 256 + threadIdx.x;   // 1M half8 groups
  const int row = idx8 >> 10;                        // 1024 half8 per row
  const float mn = rmin[row];
  const float4* v4 = (const float4*)V;
  float4 va = v4[2 * idx8];
  float4 vb = v4[2 * idx8 + 1];
  half8 o;
  o[0] = (_Float16)((va.x - mn + 1.0f) * LOG2E);
  o[1] = (_Float16)((va.y - mn + 1.0f) * LOG2E);
  o[2] = (_Float16)((va.z - mn + 1.0f) * LOG2E);
  o[3] = (_Float16)((va.w - mn + 1.0f) * LOG2E);
  o[4] = (_Float16)((vb.x - mn + 1.0f) * LOG2E);
  o[5] = (_Float16)((vb.y - mn + 1.0f) * LOG2E);
  o[6] = (_Float16)((vb.z - mn + 1.0f) * LOG2E);
  o[7] = (_Float16)((vb.w - mn + 1.0f) * LOG2E);
  ((half8*)A)[idx8] = o;
}

// ---------------- pipelined step body (R5) ----------------
// Iteration s consumes sP[s&1] (partials of e_s), produces sP[(s&1)^1]
// (partials of e_{s+1}). On entry: e = e_s, eo = e_{s-1}; on exit eo = e_{s+1}.
// acur = A row (s+1); adst receives A row (s+3).
__device__ __forceinline__ void rr_step(
    int s,
    const half8& ac0, const half8& ac1, half8& ad0, half8& ad1,
    float (&e)[16], float (&eo)[16], float (&c)[16], float& Sinv_prev,
    const half8* __restrict__ A8, half8* __restrict__ R8,
    float (*sP)[8], int t, int lane, int wave)
{
  const int par = s & 1;
  // issue the cross-wave partial read first; its ~160cy latency is hidden by
  // the Sinv-independent work below.
  float x = (lane < 8) ? sP[par][lane] : 0.0f;

  // ---- window: pack & store y_{s-1} = e_{s-1} * Sinv_{s-1} ----
  half8 o0, o1;
#pragma unroll
  for (int k = 0; k < 8; k += 2) {
    half2v h = pack_f16(eo[k] * Sinv_prev, eo[k + 1] * Sinv_prev);
    o0[k] = h[0]; o0[k + 1] = h[1];
  }
#pragma unroll
  for (int k = 0; k < 8; k += 2) {
    half2v h = pack_f16(eo[8 + k] * Sinv_prev, eo[8 + k + 1] * Sinv_prev);
    o1[k] = h[0]; o1[k + 1] = h[1];
  }
  // s=0 writes garbage y_{-1} to row 8191; overwritten by the post-loop flush.
  const size_t rrow = (size_t)((s - 1) & (STEPS - 1));
  R8[rrow * 1024 + 2 * t]     = o0;
  R8[rrow * 1024 + 2 * t + 1] = o1;

  // ---- window: t = c*e (Sinv-independent part of the c-update) ----
  float tt[16];
#pragma unroll
  for (int k = 0; k < 16; ++k) tt[k] = c[k] * e[k];

  // ---- window: prefetch A row s+3 ----
  const int ld = (s + 3) & (N_ROWS - 1);
  ad0 = A8[ld * 1024 + 2 * t];
  ad1 = A8[ld * 1024 + 2 * t + 1];

  // ---- finish cross-wave reduce -> Sinv_s ----
  x = dpp_add<0x111>(x);
  x = dpp_add<0x112>(x);
  x = dpp_add<0x114>(x);
  const float S = __builtin_bit_cast(
      float, __builtin_amdgcn_readlane(__builtin_bit_cast(int, x), 7));
  const float Sinv = fast_rcp(S);

  // ---- chain: c' = c - (c*e)*Sinv ; e_{s+1} = exp2(a_{s+1} * c') ----
  // (float)a * c + 0 matches the v_fma_mix pattern -> no separate cvt.
#pragma unroll
  for (int k = 0; k < 8; ++k) {
    c[k] = __builtin_fmaf(-tt[k], Sinv, c[k]);
    eo[k] = fast_exp2(__builtin_fmaf((float)ac0[k], c[k], 0.0f));
  }
#pragma unroll
  for (int k = 0; k < 8; ++k) {
    c[8 + k] = __builtin_fmaf(-tt[8 + k], Sinv, c[8 + k]);
    eo[8 + k] = fast_exp2(__builtin_fmaf((float)ac1[k], c[8 + k], 0.0f));
  }
  float l = (((eo[0] + eo[1]) + (eo[2] + eo[3])) + ((eo[4] + eo[5]) + (eo[6] + eo[7])))
          + (((eo[8] + eo[9]) + (eo[10] + eo[11])) + ((eo[12] + eo[13]) + (eo[14] + eo[15])));
  l = wave_sum_to_lane63(l);
  if (lane == 63) sP[par ^ 1][wave] = l;
  Sinv_prev = Sinv;
  BAR_LDS_ONLY();
}

// ---------------- main scan, store-only, pipelined: 512 thr, 16 cols/thread ----
__global__ void __launch_bounds__(512) softrr_scan_nor(const __half* __restrict__ Ah,
                                                       __half* __restrict__ Rh) {
  const int t = threadIdx.x;          // 0..511, owns cols 16t..16t+15
  const int wave = t >> 6;            // 0..7
  const int lane = t & 63;
  __shared__ float sP[2][8];

  const half8* __restrict__ A8 = (const half8*)Ah;
  half8* __restrict__ R8 = (half8*)Rh;

  float c[16], eX[16], eY[16];
#pragma unroll
  for (int k = 0; k < 16; ++k) { c[k] = 1.0f; eY[k] = 0.0f; }

  // prologue: row0 for e_0; rows 1,2 into the A ring
  half8 r0a = A8[2 * t], r0b = A8[2 * t + 1];
  half8 pA0 = A8[1024 + 2 * t], pA1 = A8[1024 + 2 * t + 1];   // row 1
  half8 pB0 = A8[2048 + 2 * t], pB1 = A8[2048 + 2 * t + 1];   // row 2
  half8 pC0, pC1, pD0, pD1;

#pragma unroll
  for (int k = 0; k < 8; ++k) {
    eX[k]     = fast_exp2((float)r0a[k]);   // c_0 = 1
    eX[8 + k] = fast_exp2((float)r0b[k]);
  }
  {
    float l = (((eX[0] + eX[1]) + (eX[2] + eX[3])) + ((eX[4] + eX[5]) + (eX[6] + eX[7])))
            + (((eX[8] + eX[9]) + (eX[10] + eX[11])) + ((eX[12] + eX[13]) + (eX[14] + eX[15])));
    l = wave_sum_to_lane63(l);
    if (lane == 63) sP[0][wave] = l;
  }
  float Sinv_prev = 0.0f;
  BAR_LDS_ONLY();

  // x4 unroll: e ping-pong period 2, A-buffer cycle period 4 -> zero movs
  for (int s = 0; s < STEPS; s += 4) {
    rr_step(s + 0, pA0, pA1, pC0, pC1, eX, eY, c, Sinv_prev, A8, R8, sP, t, lane, wave);
    rr_step(s + 1, pB0, pB1, pD0, pD1, eY, eX, c, Sinv_prev, A8, R8, sP, t, lane, wave);
    rr_step(s + 2, pC0, pC1, pA0, pA1, eX, eY, c, Sinv_prev, A8, R8, sP, t, lane, wave);
    rr_step(s + 3, pD0, pD1, pB0, pB1, eY, eX, c, Sinv_prev, A8, R8, sP, t, lane, wave);
  }

  // flush y_{8191} = e_{8191} * Sinv_{8191} (e_{8191} lives in eY after the
  // last body; this also overwrites the s=0 garbage row)
  {
    half8 o0, o1;
#pragma unroll
    for (int k = 0; k < 8; k += 2) {
      half2v h = pack_f16(eY[k] * Sinv_prev, eY[k + 1] * Sinv_prev);
      o0[k] = h[0]; o0[k + 1] = h[1];
    }
#pragma unroll
    for (int k = 0; k < 8; k += 2) {
      half2v h = pack_f16(eY[8 + k] * Sinv_prev, eY[8 + k + 1] * Sinv_prev);
      o1[k] = h[0]; o1[k + 1] = h[1];
    }
    R8[(size_t)(STEPS - 1) * 1024 + 2 * t]     = o0;
    R8[(size_t)(STEPS - 1) * 1024 + 2 * t + 1] = o1;
  }
}

// ---------------- epilogue: out[i][j] = sum_r R[r*1024+i][j] (f32) ----------------
__global__ void softrr_sum8(const __half* __restrict__ Rh, float* __restrict__ out) {
  const int idx8 = blockIdx.x * 256 + threadIdx.x;   // 1M half8 outputs
  const half8* R8 = (const half8*)Rh;
  float acc[8];
  {
    half8 v = R8[idx8];
#pragma unroll
    for (int k = 0; k < 8; ++k) acc[k] = (float)v[k];
  }
#pragma unroll
  for (int r = 1; r < 8; ++r) {
    half8 v = R8[(size_t)r * 1024 * 1024 + idx8];
#pragma unroll
    for (int k = 0; k < 8; ++k) acc[k] += (float)v[k];
  }
  ((float4*)out)[2 * idx8]     = make_float4(acc[0], acc[1], acc[2], acc[3]);
  ((float4*)out)[2 * idx8 + 1] = make_float4(acc[4], acc[5], acc[6], acc[7]);
}

// ---------------- fallback A: RMW scan (ws >= 36 MiB) ----------------
__global__ void __launch_bounds__(512) softrr_scan_a(const __half* __restrict__ Ah,
                                                     __half* __restrict__ PIh) {
  const int t = threadIdx.x;
  const int wave = t >> 6;
  const int lane = t & 63;
  __shared__ float sP[2][8];
  const half8* __restrict__ A8 = (const half8*)Ah;
  half8* __restrict__ P8 = (half8*)PIh;
  float c[16];
#pragma unroll
  for (int k = 0; k < 16; ++k) c[k] = 1.0f;
  half8 a0 = A8[2 * t];
  half8 a1 = A8[2 * t + 1];
  half8 p0, p1;
  for (int s = 0; s < STEPS; ++s) {
    const int i = s & (N_ROWS - 1);
    const int r = s >> 10;
    const int in_ = (s + 1) & (N_ROWS - 1);
    const int par = s & 1;
    half8 an0 = A8[in_ * 1024 + 2 * t];
    half8 an1 = A8[in_ * 1024 + 2 * t + 1];
    float e[16];
#pragma unroll
    for (int k = 0; k < 8; ++k) {
      e[k]     = fast_exp2((float)a0[k] * c[k]);
      e[8 + k] = fast_exp2((float)a1[k] * c[8 + k]);
    }
    float l = (((e[0] + e[1]) + (e[2] + e[3])) + ((e[4] + e[5]) + (e[6] + e[7])))
            + (((e[8] + e[9]) + (e[10] + e[11])) + ((e[12] + e[13]) + (e[14] + e[15])));
    l = wave_sum_to_lane63(l);
    if (lane == 63) sP[par][wave] = l;
    BAR_LDS_ONLY();
    float x = (lane < 8) ? sP[par][lane] : 0.0f;
    x = dpp_add<0x111>(x);
    x = dpp_add<0x112>(x);
    x = dpp_add<0x114>(x);
    const float S = __builtin_bit_cast(
        float, __builtin_amdgcn_readlane(__builtin_bit_cast(int, x), 7));
    const float Sinv = fast_rcp(S);
    half8 o0, o1;
#pragma unroll
    for (int k = 0; k < 8; k += 2) {
      float y0 = e[k] * Sinv, y1 = e[k + 1] * Sinv;
      c[k] = __builtin_fmaf(-y0, c[k], c[k]);
      c[k + 1] = __builtin_fmaf(-y1, c[k + 1], c[k + 1]);
      half2v h = pack_f16(y0, y1);
      o0[k] = h[0]; o0[k + 1] = h[1];
    }
#pragma unroll
    for (int k = 0; k < 8; k += 2) {
      float y0 = e[8 + k] * Sinv, y1 = e[8 + k + 1] * Sinv;
      c[8 + k] = __builtin_fmaf(-y0, c[8 + k], c[8 + k]);
      c[8 + k + 1] = __builtin_fmaf(-y1, c[8 + k + 1], c[8 + k + 1]);
      half2v h = pack_f16(y0, y1);
      o1[k] = h[0]; o1[k + 1] = h[1];
    }
    if (r > 0) { o0 = o0 + p0; o1 = o1 + p1; }
    P8[i * 1024 + 2 * t]     = o0;
    P8[i * 1024 + 2 * t + 1] = o1;
    a0 = an0; a1 = an1;
    p0 = P8[in_ * 1024 + 2 * t];
    p1 = P8[in_ * 1024 + 2 * t + 1];
  }
}

__global__ void softrr_cvt(const __half* __restrict__ PIh, float* __restrict__ out) {
  const int idx8 = blockIdx.x * 256 + threadIdx.x;
  half8 p = ((const half8*)PIh)[idx8];
  ((float4*)out)[2 * idx8]     = make_float4((float)p[0], (float)p[1], (float)p[2], (float)p[3]);
  ((float4*)out)[2 * idx8 + 1] = make_float4((float)p[4], (float)p[5], (float)p[6], (float)p[7]);
}

// ---------------- fallback B: f32 direct (tiny ws) ----------------
__global__ void __launch_bounds__(1024) softrr_scan_b(const float* __restrict__ V,
                                                      const float* __restrict__ rmin,
                                                      float* __restrict__ out) {
  const int t = threadIdx.x;
  const int wave = t >> 6;
  const int lane = t & 63;
  __shared__ float partials[2][16];
  __shared__ float smin[N_ROWS];
  smin[t] = rmin[t];
  __syncthreads();
  const float4* __restrict__ V4 = (const float4*)V;
  float4* O4 = (float4*)out;
  float c[8];
#pragma unroll
  for (int k = 0; k < 8; ++k) c[k] = 1.0f;
  float4 va = V4[2 * t], vb = V4[2 * t + 1];
  float4 pa, pb;
  for (int s = 0; s < STEPS; ++s) {
    const int i = s & (N_ROWS - 1);
    const int r = s >> 10;
    const int in_ = (s + 1) & (N_ROWS - 1);
    float4 van = V4[in_ * 2048 + 2 * t];
    float4 vbn = V4[in_ * 2048 + 2 * t + 1];
    const float mn = smin[i];
    const float base = (1.0f - mn) * LOG2E;
    float vv[8] = {va.x, va.y, va.z, va.w, vb.x, vb.y, vb.z, vb.w};
    float e[8];
    float l = 0.0f;
#pragma unroll
    for (int k = 0; k < 8; ++k) {
      float zb = __builtin_fmaf(vv[k], LOG2E, base);
      e[k] = fast_exp2(zb * c[k]);
      l += e[k];
    }
#pragma unroll
    for (int off = 32; off; off >>= 1) l += __shfl_xor(l, off, 64);
    if (lane == 0) partials[s & 1][wave] = l;
    __syncthreads();
    float S = 0.0f;
#pragma unroll
    for (int w = 0; w < 16; ++w) S += partials[s & 1][w];
    const float Sinv = fast_rcp(S);
    float po[8] = {pa.x, pa.y, pa.z, pa.w, pb.x, pb.y, pb.z, pb.w};
    float o[8];
#pragma unroll
    for (int k = 0; k < 8; ++k) {
      float y = e[k] * Sinv;
      c[k] = __builtin_fmaf(-y, c[k], c[k]);
      o[k] = (r > 0) ? (po[k] + y) : y;
    }
    O4[i * 2048 + 2 * t]     = make_float4(o[0], o[1], o[2], o[3]);
    O4[i * 2048 + 2 * t + 1] = make_float4(o[4], o[5], o[6], o[7]);
    va = van; vb = vbn;
    pa = O4[in_ * 2048 + 2 * t];
    pb = O4[in_ * 2048 + 2 * t + 1];
  }
}

extern "C" void kernel_launch(void* const* d_in, const int* in_sizes, int n_in,
                              void* d_out, int out_size, void* d_ws, size_t ws_size,
                              hipStream_t stream) {
  const float* V = (const float*)d_in[0];
  float* out = (float*)d_out;
  float* rmin = (float*)d_ws;

  const size_t A_BYTES = (size_t)N_ROWS * M_COLS * 2;          // 16 MiB
  const size_t R_BYTES = (size_t)STEPS * M_COLS * 2;           // 128 MiB
  const size_t need_nor = 4096 + A_BYTES + R_BYTES;            // ~144 MiB
  const size_t need_rmw = 4096 + A_BYTES + A_BYTES;            // ~32 MiB

  if (ws_size >= need_nor) {
    __half* A = (__half*)((char*)d_ws + 4096);
    __half* R = (__half*)((char*)d_ws + 4096 + A_BYTES);
    softrr_rowmin<<<N_ROWS, 256, 0, stream>>>(V, rmin);
    softrr_prep<<<4096, 256, 0, stream>>>(V, rmin, A);
    softrr_scan_nor<<<1, 512, 0, stream>>>(A, R);
    softrr_sum8<<<4096, 256, 0, stream>>>(R, out);
  } else if (ws_size >= need_rmw) {
    __half* A  = (__half*)((char*)d_ws + 4096);
    __half* PI = (__half*)((char*)d_ws + 4096 + A_BYTES);
    softrr_rowmin<<<N_ROWS, 256, 0, stream>>>(V, rmin);
    softrr_prep<<<4096, 256, 0, stream>>>(V, rmin, A);
    softrr_scan_a<<<1, 512, 0, stream>>>(A, PI);
    softrr_cvt<<<4096, 256, 0, stream>>>(PI, out);
  } else {
    softrr_rowmin<<<N_ROWS, 256, 0, stream>>>(V, rmin);
    softrr_scan_b<<<1, 1024, 0, stream>>>(V, rmin, out);
  }
}

// Round 2
// 4288.250 us; speedup vs baseline: 1.1595x; 1.1595x over previous
//
#include <hip/hip_runtime.h>
#include <hip/hip_fp16.h>

// SoftRR: n=1024, m=8192, rounds=8, TAU=1.0
//   scan over 8192 rows (V tiled x8):
//     y = softmax((row - min(row) + 1) * c);  c = (1-y)*c
//   pi[i][j] = sum over rounds of y
//
// R6: 16-wave scan + lean math. R5's chain-restructure was NULL (4876 vs 4860us)
// => not chain-bound; issue-bound + unhidden barrier window with only 2
// waves/SIMD. Changes:
//   - 1024 threads (16 waves, 4/SIMD), 8 cols/thread: same total issue, but
//     4 waves/SIMD hide the post-barrier sP-read + DPP chain and barrier skew.
//   - lean per-col math: y = e*Sinv (reused for c-update, no tt-muls),
//     in-place e[] (no ping-pong), y packed to f16 at the step TAIL (dead
//     time before barrier), stored in the next step's window.
//   - A-row kept as 1 half8/thread, 4-buffer rotation, prefetch 3 ahead.

#define N_ROWS 1024
#define M_COLS 8192
#define STEPS  8192
#define LOG2E  1.4426950408889634f

using half8  = __attribute__((ext_vector_type(8))) _Float16;
using half2v = __attribute__((ext_vector_type(2))) _Float16;

__device__ __forceinline__ float fast_exp2(float x) {
#if __has_builtin(__builtin_amdgcn_exp2f)
  return __builtin_amdgcn_exp2f(x);
#else
  return exp2f(x);
#endif
}
__device__ __forceinline__ float fast_rcp(float x) {
#if __has_builtin(__builtin_amdgcn_rcpf)
  return __builtin_amdgcn_rcpf(x);
#else
  return 1.0f / x;
#endif
}
__device__ __forceinline__ half2v pack_f16(float y0, float y1) {
  return __builtin_bit_cast(half2v, __builtin_amdgcn_cvt_pkrtz(y0, y1));
}

template <int CTRL>
__device__ __forceinline__ float dpp_add(float x) {
  int yi = __builtin_amdgcn_update_dpp(0, __builtin_bit_cast(int, x),
                                       CTRL, 0xf, 0xf, true);
  return x + __builtin_bit_cast(float, yi);
}

// full 64-lane sum; result valid in lane 63
__device__ __forceinline__ float wave_sum_to_lane63(float x) {
  x = dpp_add<0x111>(x);  // row_shr:1
  x = dpp_add<0x112>(x);  // row_shr:2
  x = dpp_add<0x114>(x);  // row_shr:4
  x = dpp_add<0x118>(x);  // row_shr:8   -> lane15 of each row = row sum
  x = dpp_add<0x142>(x);  // row_bcast15
  x = dpp_add<0x143>(x);  // row_bcast31 -> lane63 = total
  return x;
}

// barrier WITHOUT vmcnt drain: only LDS ops must be visible across it
#define BAR_LDS_ONLY() asm volatile("s_waitcnt lgkmcnt(0)\n\ts_barrier" ::: "memory")

// ---------------- rowmin: one block per row ----------------
__global__ void softrr_rowmin(const float* __restrict__ V, float* __restrict__ rmin) {
  const int row = blockIdx.x;
  const float* p = V + (size_t)row * M_COLS;
  float m = 1e30f;
  for (int j = threadIdx.x; j < M_COLS; j += 256) m = fminf(m, p[j]);
#pragma unroll
  for (int off = 32; off; off >>= 1) m = fminf(m, __shfl_xor(m, off, 64));
  __shared__ float sm[4];
  if ((threadIdx.x & 63) == 0) sm[threadIdx.x >> 6] = m;
  __syncthreads();
  if (threadIdx.x == 0) {
    rmin[row] = fminf(fminf(sm[0], sm[1]), fminf(sm[2], sm[3]));
  }
}

// ---------------- prep: a = (V - rowmin + 1) * log2e, fp16 ----------------
__global__ void softrr_prep(const float* __restrict__ V, const float* __restrict__ rmin,
                            __half* __restrict__ A) {
  const int idx8 = blockIdx.x * 256 + threadIdx.x;   // 1M half8 groups
  const int row = idx8 >> 10;                        // 1024 half8 per row
  const float mn = rmin[row];
  const float4* v4 = (const float4*)V;
  float4 va = v4[2 * idx8];
  float4 vb = v4[2 * idx8 + 1];
  half8 o;
  o[0] = (_Float16)((va.x - mn + 1.0f) * LOG2E);
  o[1] = (_Float16)((va.y - mn + 1.0f) * LOG2E);
  o[2] = (_Float16)((va.z - mn + 1.0f) * LOG2E);
  o[3] = (_Float16)((va.w - mn + 1.0f) * LOG2E);
  o[4] = (_Float16)((vb.x - mn + 1.0f) * LOG2E);
  o[5] = (_Float16)((vb.y - mn + 1.0f) * LOG2E);
  o[6] = (_Float16)((vb.z - mn + 1.0f) * LOG2E);
  o[7] = (_Float16)((vb.w - mn + 1.0f) * LOG2E);
  ((half8*)A)[idx8] = o;
}

// ---------------- pipelined step body (R6, 1024 thr) ----------------
// On entry: e[] = e_s, o = packed y_{s-1}, sP[s&1] = partials of e_s,
// acur = A row (s+1). On exit: e[] = e_{s+1}, o = packed y_s,
// sP[(s&1)^1] = partials of e_{s+1}; adst <- A row (s+3).
__device__ __forceinline__ void rr_step(
    int s,
    const half8& acur, half8& adst,
    float (&e)[8], float (&c)[8], half8& o,
    const half8* __restrict__ A8, half8* __restrict__ R8,
    float (*sP)[16], int t, int lane, int wave)
{
  const int par = s & 1;
  // issue the cross-wave partial read first; latency hidden by window work
  float x = (lane < 16) ? sP[par][lane] : 0.0f;

  // ---- window: store y_{s-1} (s=0 stores init garbage to row 8191,
  //      overwritten by the post-loop flush) ----
  R8[(size_t)((s - 1) & (STEPS - 1)) * 1024 + t] = o;

  // ---- window: prefetch A row s+3 ----
  adst = A8[((s + 3) & (N_ROWS - 1)) * 1024 + t];

  // ---- finish cross-wave reduce -> Sinv ----
  x = dpp_add<0x111>(x);
  x = dpp_add<0x112>(x);
  x = dpp_add<0x114>(x);
  x = dpp_add<0x118>(x);   // lane15 = total of 16 partials
  const float S = __builtin_bit_cast(
      float, __builtin_amdgcn_readlane(__builtin_bit_cast(int, x), 15));
  const float Sinv = fast_rcp(S);

  // ---- chain: y = e*Sinv; c' = c - y*c; e' = exp2(a*c') ----
  float y[8];
#pragma unroll
  for (int k = 0; k < 8; ++k) {
    y[k] = e[k] * Sinv;
    c[k] = __builtin_fmaf(-y[k], c[k], c[k]);
    e[k] = fast_exp2(__builtin_fmaf((float)acur[k], c[k], 0.0f));  // v_fma_mix
  }
  float l = ((e[0] + e[1]) + (e[2] + e[3])) + ((e[4] + e[5]) + (e[6] + e[7]));
  l = wave_sum_to_lane63(l);
  if (lane == 63) sP[par ^ 1][wave] = l;

  // ---- tail (dead time before barrier): pack y_s for next-step store ----
  {
    half2v h0 = pack_f16(y[0], y[1]);
    half2v h1 = pack_f16(y[2], y[3]);
    half2v h2 = pack_f16(y[4], y[5]);
    half2v h3 = pack_f16(y[6], y[7]);
    o[0] = h0[0]; o[1] = h0[1]; o[2] = h1[0]; o[3] = h1[1];
    o[4] = h2[0]; o[5] = h2[1]; o[6] = h3[0]; o[7] = h3[1];
  }
  BAR_LDS_ONLY();
}

// ---------------- main scan, store-only: 1024 thr (16 waves), 8 cols/thread ----
__global__ void __launch_bounds__(1024) softrr_scan_nor(const __half* __restrict__ Ah,
                                                        __half* __restrict__ Rh) {
  const int t = threadIdx.x;          // 0..1023, owns cols 8t..8t+7
  const int wave = t >> 6;            // 0..15
  const int lane = t & 63;
  __shared__ float sP[2][16];

  const half8* __restrict__ A8 = (const half8*)Ah;
  half8* __restrict__ R8 = (half8*)Rh;

  float c[8], e[8];
#pragma unroll
  for (int k = 0; k < 8; ++k) c[k] = 1.0f;

  // prologue: row0 -> e_0; rows 1,2 into the A ring
  half8 r0 = A8[t];
  half8 pA = A8[1024 + t];    // row 1
  half8 pB = A8[2048 + t];    // row 2
  half8 pC, pD;

#pragma unroll
  for (int k = 0; k < 8; ++k) e[k] = fast_exp2((float)r0[k]);   // c_0 = 1
  {
    float l = ((e[0] + e[1]) + (e[2] + e[3])) + ((e[4] + e[5]) + (e[6] + e[7]));
    l = wave_sum_to_lane63(l);
    if (lane == 63) sP[0][wave] = l;
  }
  half8 o;   // packed y_{s-1}; init value only reaches row 8191 (re-flushed)
  {
    half2v z = pack_f16(0.0f, 0.0f);
    o[0]=z[0]; o[1]=z[1]; o[2]=z[0]; o[3]=z[1];
    o[4]=z[0]; o[5]=z[1]; o[6]=z[0]; o[7]=z[1];
  }
  BAR_LDS_ONLY();

  // x4 unroll: A-buffer cycle period 4 -> zero rotation movs
  for (int s = 0; s < STEPS; s += 4) {
    rr_step(s + 0, pA, pC, e, c, o, A8, R8, sP, t, lane, wave);
    rr_step(s + 1, pB, pD, e, c, o, A8, R8, sP, t, lane, wave);
    rr_step(s + 2, pC, pA, e, c, o, A8, R8, sP, t, lane, wave);
    rr_step(s + 3, pD, pB, e, c, o, A8, R8, sP, t, lane, wave);
  }

  // flush y_{8191} (lives packed in o; also overwrites the s=0 garbage row)
  R8[(size_t)(STEPS - 1) * 1024 + t] = o;
}

// ---------------- epilogue: out[i][j] = sum_r R[r*1024+i][j] (f32) ----------------
__global__ void softrr_sum8(const __half* __restrict__ Rh, float* __restrict__ out) {
  const int idx8 = blockIdx.x * 256 + threadIdx.x;   // 1M half8 outputs
  const half8* R8 = (const half8*)Rh;
  float acc[8];
  {
    half8 v = R8[idx8];
#pragma unroll
    for (int k = 0; k < 8; ++k) acc[k] = (float)v[k];
  }
#pragma unroll
  for (int r = 1; r < 8; ++r) {
    half8 v = R8[(size_t)r * 1024 * 1024 + idx8];
#pragma unroll
    for (int k = 0; k < 8; ++k) acc[k] += (float)v[k];
  }
  ((float4*)out)[2 * idx8]     = make_float4(acc[0], acc[1], acc[2], acc[3]);
  ((float4*)out)[2 * idx8 + 1] = make_float4(acc[4], acc[5], acc[6], acc[7]);
}

// ---------------- fallback A: RMW scan (ws >= 36 MiB) ----------------
__global__ void __launch_bounds__(512) softrr_scan_a(const __half* __restrict__ Ah,
                                                     __half* __restrict__ PIh) {
  const int t = threadIdx.x;
  const int wave = t >> 6;
  const int lane = t & 63;
  __shared__ float sP[2][8];
  const half8* __restrict__ A8 = (const half8*)Ah;
  half8* __restrict__ P8 = (half8*)PIh;
  float c[16];
#pragma unroll
  for (int k = 0; k < 16; ++k) c[k] = 1.0f;
  half8 a0 = A8[2 * t];
  half8 a1 = A8[2 * t + 1];
  half8 p0, p1;
  for (int s = 0; s < STEPS; ++s) {
    const int i = s & (N_ROWS - 1);
    const int r = s >> 10;
    const int in_ = (s + 1) & (N_ROWS - 1);
    const int par = s & 1;
    half8 an0 = A8[in_ * 1024 + 2 * t];
    half8 an1 = A8[in_ * 1024 + 2 * t + 1];
    float e[16];
#pragma unroll
    for (int k = 0; k < 8; ++k) {
      e[k]     = fast_exp2((float)a0[k] * c[k]);
      e[8 + k] = fast_exp2((float)a1[k] * c[8 + k]);
    }
    float l = (((e[0] + e[1]) + (e[2] + e[3])) + ((e[4] + e[5]) + (e[6] + e[7])))
            + (((e[8] + e[9]) + (e[10] + e[11])) + ((e[12] + e[13]) + (e[14] + e[15])));
    l = wave_sum_to_lane63(l);
    if (lane == 63) sP[par][wave] = l;
    BAR_LDS_ONLY();
    float x = (lane < 8) ? sP[par][lane] : 0.0f;
    x = dpp_add<0x111>(x);
    x = dpp_add<0x112>(x);
    x = dpp_add<0x114>(x);
    const float S = __builtin_bit_cast(
        float, __builtin_amdgcn_readlane(__builtin_bit_cast(int, x), 7));
    const float Sinv = fast_rcp(S);
    half8 o0, o1;
#pragma unroll
    for (int k = 0; k < 8; k += 2) {
      float y0 = e[k] * Sinv, y1 = e[k + 1] * Sinv;
      c[k] = __builtin_fmaf(-y0, c[k], c[k]);
      c[k + 1] = __builtin_fmaf(-y1, c[k + 1], c[k + 1]);
      half2v h = pack_f16(y0, y1);
      o0[k] = h[0]; o0[k + 1] = h[1];
    }
#pragma unroll
    for (int k = 0; k < 8; k += 2) {
      float y0 = e[8 + k] * Sinv, y1 = e[8 + k + 1] * Sinv;
      c[8 + k] = __builtin_fmaf(-y0, c[8 + k], c[8 + k]);
      c[8 + k + 1] = __builtin_fmaf(-y1, c[8 + k + 1], c[8 + k + 1]);
      half2v h = pack_f16(y0, y1);
      o1[k] = h[0]; o1[k + 1] = h[1];
    }
    if (r > 0) { o0 = o0 + p0; o1 = o1 + p1; }
    P8[i * 1024 + 2 * t]     = o0;
    P8[i * 1024 + 2 * t + 1] = o1;
    a0 = an0; a1 = an1;
    p0 = P8[in_ * 1024 + 2 * t];
    p1 = P8[in_ * 1024 + 2 * t + 1];
  }
}

__global__ void softrr_cvt(const __half* __restrict__ PIh, float* __restrict__ out) {
  const int idx8 = blockIdx.x * 256 + threadIdx.x;
  half8 p = ((const half8*)PIh)[idx8];
  ((float4*)out)[2 * idx8]     = make_float4((float)p[0], (float)p[1], (float)p[2], (float)p[3]);
  ((float4*)out)[2 * idx8 + 1] = make_float4((float)p[4], (float)p[5], (float)p[6], (float)p[7]);
}

// ---------------- fallback B: f32 direct (tiny ws) ----------------
__global__ void __launch_bounds__(1024) softrr_scan_b(const float* __restrict__ V,
                                                      const float* __restrict__ rmin,
                                                      float* __restrict__ out) {
  const int t = threadIdx.x;
  const int wave = t >> 6;
  const int lane = t & 63;
  __shared__ float partials[2][16];
  __shared__ float smin[N_ROWS];
  smin[t] = rmin[t];
  __syncthreads();
  const float4* __restrict__ V4 = (const float4*)V;
  float4* O4 = (float4*)out;
  float c[8];
#pragma unroll
  for (int k = 0; k < 8; ++k) c[k] = 1.0f;
  float4 va = V4[2 * t], vb = V4[2 * t + 1];
  float4 pa, pb;
  for (int s = 0; s < STEPS; ++s) {
    const int i = s & (N_ROWS - 1);
    const int r = s >> 10;
    const int in_ = (s + 1) & (N_ROWS - 1);
    float4 van = V4[in_ * 2048 + 2 * t];
    float4 vbn = V4[in_ * 2048 + 2 * t + 1];
    const float mn = smin[i];
    const float base = (1.0f - mn) * LOG2E;
    float vv[8] = {va.x, va.y, va.z, va.w, vb.x, vb.y, vb.z, vb.w};
    float e[8];
    float l = 0.0f;
#pragma unroll
    for (int k = 0; k < 8; ++k) {
      float zb = __builtin_fmaf(vv[k], LOG2E, base);
      e[k] = fast_exp2(zb * c[k]);
      l += e[k];
    }
#pragma unroll
    for (int off = 32; off; off >>= 1) l += __shfl_xor(l, off, 64);
    if (lane == 0) partials[s & 1][wave] = l;
    __syncthreads();
    float S = 0.0f;
#pragma unroll
    for (int w = 0; w < 16; ++w) S += partials[s & 1][w];
    const float Sinv = fast_rcp(S);
    float po[8] = {pa.x, pa.y, pa.z, pa.w, pb.x, pb.y, pb.z, pb.w};
    float o[8];
#pragma unroll
    for (int k = 0; k < 8; ++k) {
      float y = e[k] * Sinv;
      c[k] = __builtin_fmaf(-y, c[k], c[k]);
      o[k] = (r > 0) ? (po[k] + y) : y;
    }
    O4[i * 2048 + 2 * t]     = make_float4(o[0], o[1], o[2], o[3]);
    O4[i * 2048 + 2 * t + 1] = make_float4(o[4], o[5], o[6], o[7]);
    va = van; vb = vbn;
    pa = O4[in_ * 2048 + 2 * t];
    pb = O4[in_ * 2048 + 2 * t + 1];
  }
}

extern "C" void kernel_launch(void* const* d_in, const int* in_sizes, int n_in,
                              void* d_out, int out_size, void* d_ws, size_t ws_size,
                              hipStream_t stream) {
  const float* V = (const float*)d_in[0];
  float* out = (float*)d_out;
  float* rmin = (float*)d_ws;

  const size_t A_BYTES = (size_t)N_ROWS * M_COLS * 2;          // 16 MiB
  const size_t R_BYTES = (size_t)STEPS * M_COLS * 2;           // 128 MiB
  const size_t need_nor = 4096 + A_BYTES + R_BYTES;            // ~144 MiB
  const size_t need_rmw = 4096 + A_BYTES + A_BYTES;            // ~32 MiB

  if (ws_size >= need_nor) {
    __half* A = (__half*)((char*)d_ws + 4096);
    __half* R = (__half*)((char*)d_ws + 4096 + A_BYTES);
    softrr_rowmin<<<N_ROWS, 256, 0, stream>>>(V, rmin);
    softrr_prep<<<4096, 256, 0, stream>>>(V, rmin, A);
    softrr_scan_nor<<<1, 1024, 0, stream>>>(A, R);
    softrr_sum8<<<4096, 256, 0, stream>>>(R, out);
  } else if (ws_size >= need_rmw) {
    __half* A  = (__half*)((char*)d_ws + 4096);
    __half* PI = (__half*)((char*)d_ws + 4096 + A_BYTES);
    softrr_rowmin<<<N_ROWS, 256, 0, stream>>>(V, rmin);
    softrr_prep<<<4096, 256, 0, stream>>>(V, rmin, A);
    softrr_scan_a<<<1, 512, 0, stream>>>(A, PI);
    softrr_cvt<<<4096, 256, 0, stream>>>(PI, out);
  } else {
    softrr_rowmin<<<N_ROWS, 256, 0, stream>>>(V, rmin);
    softrr_scan_b<<<1, 1024, 0, stream>>>(V, rmin, out);
  }
}